// Round 8
// baseline (100.608 us; speedup 1.0000x reference)
//
#include <hip/hip_runtime.h>

#define N_ELEM 95
#define MAX_NODES 100096           // LDS byte-table capacity for k_split
#define ZW_WORDS (MAX_NODES / 4)   // 25024 u32 words = 100096 B
#define RS 33792                   // nodes per range (132 KB LDS in k_accum2)
#define MAX_R 4
#define EB 256                     // k_split blocks

typedef float f32x4 __attribute__((ext_vector_type(4)));
typedef int   i32x4 __attribute__((ext_vector_type(4)));
typedef unsigned int u32;
typedef u32 u32x4 __attribute__((ext_vector_type(4)));

__device__ __forceinline__ u32 bf16_rtn(float f) {
    u32 u = __float_as_uint(f);
    return (u + 0x7FFFu + ((u >> 16) & 1u)) >> 16;
}

// ---------- pack z (int32, values 1..94) into bytes in workspace ----------
__global__ __launch_bounds__(256) void k_pack(
    const int* __restrict__ z, u32* __restrict__ zw, int n_words, int n)
{
    int w = blockIdx.x * blockDim.x + threadIdx.x;
    if (w < n_words) {
        int i = w << 2;
        u32 b0 = (i + 0 < n) ? (u32)z[i + 0] & 0xff : 0u;
        u32 b1 = (i + 1 < n) ? (u32)z[i + 1] & 0xff : 0u;
        u32 b2 = (i + 2 < n) ? (u32)z[i + 2] & 0xff : 0u;
        u32 b3 = (i + 3 < n) ? (u32)z[i + 3] & 0xff : 0u;
        zw[w] = b0 | (b1 << 8) | (b2 << 16) | (b3 << 24);
    }
}

// ---------- k_split: compute values, emit nonzero edges to range streams ----
__global__ __launch_bounds__(1024) void k_split(
    const u32*   __restrict__ zw,
    const float* __restrict__ dist,
    const int*   __restrict__ sender,
    const int*   __restrict__ recv,
    const float* __restrict__ a_factor_p,
    const float* __restrict__ z_power_p,
    const float* __restrict__ coefs,
    const float* __restrict__ exps,
    const float* __restrict__ cradii,
    u32*         __restrict__ seg,      // [EB][Rr][CAP]
    u32*         __restrict__ counts,   // [EB][Rr]
    float*       __restrict__ ovf,      // [Rr*RS], pre-zeroed
    int n_edges, int n_words, int W, int CAP, int Rr)
{
    __shared__ u32    s_zw[ZW_WORDS];
    __shared__ float2 s_tab[N_ELEM];   // {Z^Z_power, covalent_radius}
    __shared__ float  s_coef[4], s_exp[4], s_inv;
    __shared__ u32    lcur[MAX_R];

    const int tid = threadIdx.x;
    for (int i = tid; i < n_words; i += 1024) s_zw[i] = zw[i];
    if (tid < N_ELEM) {
        float zp = z_power_p[0];
        s_tab[tid] = make_float2(__powf((float)tid, zp), cradii[tid]);
    }
    if (tid < 4) { s_coef[tid] = coefs[tid]; s_exp[tid] = exps[tid]; }
    if (tid < MAX_R) lcur[tid] = 0u;
    if (tid == 0) s_inv = 1.0f / (a_factor_p[0] * 0.529f);
    __syncthreads();

    const unsigned char* s_zb = (const unsigned char*)s_zw;
    const float inv_pref = s_inv;
    const float c0 = s_coef[0], c1 = s_coef[1], c2 = s_coef[2], c3 = s_coef[3];
    const float e0 = s_exp[0],  e1 = s_exp[1],  e2 = s_exp[2],  e3 = s_exp[3];

    const int b  = blockIdx.x;
    const int e0i = b * W;
    const int e1i = min(n_edges, e0i + W);
    const int lane = tid & 63;

    u32* __restrict__ segb = seg + (size_t)b * Rr * CAP;

    // vector main loop: 8 edges per thread-iteration (W is a multiple of 8)
    for (int base = e0i + (tid << 3); base + 8 <= e1i; base += (1024 << 3)) {
        const int g = base >> 3;
        const f32x4 dA = __builtin_nontemporal_load((const f32x4*)dist + 2 * g);
        const f32x4 dB = __builtin_nontemporal_load((const f32x4*)dist + 2 * g + 1);
        const i32x4 sA = __builtin_nontemporal_load((const i32x4*)sender + 2 * g);
        const i32x4 sB = __builtin_nontemporal_load((const i32x4*)sender + 2 * g + 1);
        const i32x4 rA = __builtin_nontemporal_load((const i32x4*)recv + 2 * g);
        const i32x4 rB = __builtin_nontemporal_load((const i32x4*)recv + 2 * g + 1);

        float dd[8] = {dA.x, dA.y, dA.z, dA.w, dB.x, dB.y, dB.z, dB.w};
        int   ss[8] = {sA.x, sA.y, sA.z, sA.w, sB.x, sB.y, sB.z, sB.w};
        int   rr[8] = {rA.x, rA.y, rA.z, rA.w, rB.x, rB.y, rB.z, rB.w};

        int zu[8], zv[8];
        #pragma unroll
        for (int k = 0; k < 8; ++k) zu[k] = s_zb[ss[k]];
        #pragma unroll
        for (int k = 0; k < 8; ++k) zv[k] = s_zb[rr[k]];

        float vv[8];
        bool  em[8];
        #pragma unroll
        for (int k = 0; k < 8; ++k) {
            const float d = dd[k];
            const float2 tu = s_tab[zu[k]];
            const float2 tv = s_tab[zv[k]];
            const float rmax = tu.y + tv.y;
            em[k] = (d < rmax);
            float o = 0.0f;
            if (em[k]) {
                const float t   = __fdividef(d, rmax);
                const float roa = d * (tu.x + tv.x) * inv_pref;
                const float phi = c0 * __expf(-e0 * roa)
                                + c1 * __expf(-e1 * roa)
                                + c2 * __expf(-e2 * roa)
                                + c3 * __expf(-e3 * roa);
                const float v   = 7.1998f * (float)(zu[k] * zv[k]) * phi
                                * __fdividef(1.0f, d);
                const float t2  = t * t;
                const float t6  = t2 * t2 * t2;
                // p=6: 1 - 28 t^6 + 48 t^7 - 21 t^8
                o = v * (1.0f - t6 * (28.0f - 48.0f * t + 21.0f * t2));
            }
            vv[k] = o;
        }

        // wave-aggregated emit
        #pragma unroll
        for (int k = 0; k < 8; ++k) {
            const u32 rv   = (u32)rr[k];
            const u32 rg   = rv / (u32)RS;
            const u32 slot = rv - rg * (u32)RS;
            const u32 pk   = (slot << 16) | bf16_rtn(vv[k]);
            for (u32 r = 0; r < (u32)Rr; ++r) {
                const bool mine = em[k] && (rg == r);
                const unsigned long long m = __ballot(mine);
                if (m != 0ULL) {
                    const int leader = __builtin_ctzll(m);
                    u32 wbase = 0;
                    if (lane == leader)
                        wbase = atomicAdd(&lcur[r], (u32)__popcll(m));
                    wbase = __shfl(wbase, leader, 64);
                    if (mine) {
                        u32 mb = __builtin_amdgcn_mbcnt_lo((u32)m, 0u);
                        mb = __builtin_amdgcn_mbcnt_hi((u32)(m >> 32), mb);
                        const u32 pos = wbase + mb;
                        if (pos < (u32)CAP) segb[r * (u32)CAP + pos] = pk;
                        else unsafeAtomicAdd(&ovf[rv], vv[k]);
                    }
                }
            }
        }
    }

    // scalar tail (last partial group of the block's window)
    const int nfull = (e1i - e0i) & ~7;
    for (int i = e0i + nfull + tid; i < e1i; i += 1024) {
        const float d  = dist[i];
        const int   a  = s_zb[sender[i]];
        const u32   rv = (u32)recv[i];
        const int   bb = s_zb[rv];
        const float2 tu = s_tab[a];
        const float2 tv = s_tab[bb];
        const float rmax = tu.y + tv.y;
        if (d < rmax) {
            const float t   = __fdividef(d, rmax);
            const float roa = d * (tu.x + tv.x) * inv_pref;
            const float phi = c0 * __expf(-e0 * roa)
                            + c1 * __expf(-e1 * roa)
                            + c2 * __expf(-e2 * roa)
                            + c3 * __expf(-e3 * roa);
            const float v   = 7.1998f * (float)(a * bb) * phi * __fdividef(1.0f, d);
            const float t2  = t * t;
            const float t6  = t2 * t2 * t2;
            const float o   = v * (1.0f - t6 * (28.0f - 48.0f * t + 21.0f * t2));
            const u32 rg    = rv / (u32)RS;
            const u32 slot  = rv - rg * (u32)RS;
            const u32 pos   = atomicAdd(&lcur[rg], 1u);
            if (pos < (u32)CAP) segb[rg * (u32)CAP + pos] = (slot << 16) | bf16_rtn(o);
            else unsafeAtomicAdd(&ovf[rv], o);
        }
    }

    __syncthreads();
    if (tid < Rr)
        counts[b * Rr + tid] = min(lcur[tid], (u32)CAP);
}

// ---------- k_accum2: single-read per-range LDS accumulation ----------
__global__ __launch_bounds__(1024) void k_accum2(
    const u32* __restrict__ seg,
    const u32* __restrict__ counts,
    float*     __restrict__ copies,
    int C, int Rr, int CAP)
{
    __shared__ float acc[RS];
    const int c = blockIdx.x % C;    // chunk of k_split blocks
    const int r = blockIdx.x / C;    // node range
    const int tid = threadIdx.x;

    for (int i = tid; i < RS; i += 1024) acc[i] = 0.0f;
    __syncthreads();

    for (int b = c; b < EB; b += C) {
        const u32 cnt = counts[b * Rr + r];
        const u32* __restrict__ p = seg + ((size_t)b * Rr + r) * CAP;
        const int n4 = (int)(cnt >> 2);
        for (int q = tid; q < n4; q += 1024) {
            const u32x4 w = ((const u32x4*)p)[q];
            atomicAdd(&acc[w.x >> 16], __uint_as_float((w.x & 0xFFFFu) << 16));
            atomicAdd(&acc[w.y >> 16], __uint_as_float((w.y & 0xFFFFu) << 16));
            atomicAdd(&acc[w.z >> 16], __uint_as_float((w.z & 0xFFFFu) << 16));
            atomicAdd(&acc[w.w >> 16], __uint_as_float((w.w & 0xFFFFu) << 16));
        }
        for (int i = (n4 << 2) + tid; i < (int)cnt; i += 1024) {
            const u32 w = p[i];
            atomicAdd(&acc[w >> 16], __uint_as_float((w & 0xFFFFu) << 16));
        }
    }
    __syncthreads();

    float* __restrict__ dst = copies + ((size_t)c * Rr + r) * RS;
    for (int i = tid * 4; i < RS; i += 4096)
        *(f32x4*)(dst + i) = *(const f32x4*)(acc + i);
}

// ---------- k_final2: sum private copies + overflow ----------
__global__ __launch_bounds__(256) void k_final2(
    const float* __restrict__ copies,
    const float* __restrict__ ovf,
    float* __restrict__ out,
    int n_nodes, int C, int RRS)
{
    const int n = blockIdx.x * 256 + threadIdx.x;
    if (n < n_nodes) {
        float s = ovf[n];
        for (int c = 0; c < C; ++c) s += copies[(size_t)c * RRS + n];
        out[n] = s;
    }
}

// ---------- fallback: R5 path (LDS z-table + direct atomics) ----------
__global__ __launch_bounds__(1024) void zbl_edge_lds(
    const u32* __restrict__ zw, const float* __restrict__ dist,
    const int* __restrict__ sender, const int* __restrict__ recv,
    const float* __restrict__ a_factor_p, const float* __restrict__ z_power_p,
    const float* __restrict__ coefs, const float* __restrict__ exps,
    const float* __restrict__ cradii, float* __restrict__ out,
    int n_edges, int n_words)
{
    __shared__ u32    s_zw[ZW_WORDS];
    __shared__ float2 s_tab[N_ELEM];
    __shared__ float  s_coef[4], s_exp[4], s_inv;
    const int tid = threadIdx.x;
    for (int i = tid; i < n_words; i += 1024) s_zw[i] = zw[i];
    if (tid < N_ELEM) {
        float zp = z_power_p[0];
        s_tab[tid] = make_float2(__powf((float)tid, zp), cradii[tid]);
    }
    if (tid < 4) { s_coef[tid] = coefs[tid]; s_exp[tid] = exps[tid]; }
    if (tid == 0) s_inv = 1.0f / (a_factor_p[0] * 0.529f);
    __syncthreads();
    const unsigned char* s_zb = (const unsigned char*)s_zw;
    const float inv_pref = s_inv;
    const int gstride = gridDim.x * 1024;
    for (int i = blockIdx.x * 1024 + tid; i < n_edges; i += gstride) {
        const float d  = dist[i];
        const int   a  = s_zb[sender[i]];
        const int   rv = recv[i];
        const int   b  = s_zb[rv];
        const float2 tu = s_tab[a];
        const float2 tv = s_tab[b];
        const float rmax = tu.y + tv.y;
        if (d < rmax) {
            const float t   = __fdividef(d, rmax);
            const float roa = d * (tu.x + tv.x) * inv_pref;
            const float phi = s_coef[0] * __expf(-s_exp[0] * roa)
                            + s_coef[1] * __expf(-s_exp[1] * roa)
                            + s_coef[2] * __expf(-s_exp[2] * roa)
                            + s_coef[3] * __expf(-s_exp[3] * roa);
            const float v   = 7.1998f * (float)(a * b) * phi * __fdividef(1.0f, d);
            const float t2  = t * t;
            const float t6  = t2 * t2 * t2;
            const float env = 1.0f - t6 * (28.0f - 48.0f * t + 21.0f * t2);
            unsafeAtomicAdd(&out[rv], v * env);
        }
    }
}

static inline size_t align16(size_t x) { return (x + 15) & ~(size_t)15; }

extern "C" void kernel_launch(void* const* d_in, const int* in_sizes, int n_in,
                              void* d_out, int out_size, void* d_ws, size_t ws_size,
                              hipStream_t stream) {
    const int*   z        = (const int*)d_in[0];
    const float* dist     = (const float*)d_in[1];
    const int*   eidx     = (const int*)d_in[2];
    const float* a_factor = (const float*)d_in[3];
    const float* z_power  = (const float*)d_in[4];
    const float* coefs    = (const float*)d_in[5];
    const float* exps     = (const float*)d_in[6];
    const float* cradii   = (const float*)d_in[7];
    float* out = (float*)d_out;

    const int n_edges = in_sizes[1];
    const int n_nodes = out_size;
    const int* sender = eidx;
    const int* recv   = eidx + n_edges;

    const int n_words = (n_nodes + 3) >> 2;
    const int R = (n_nodes + RS - 1) / RS;
    const int W = (((n_edges + EB - 1) / EB) + 7) & ~7;   // per-block window, x8

    // ws layout: [zw][counts][ovf][copies][seg...]
    const size_t off_zw     = 0;
    const size_t off_counts = align16((size_t)n_words * sizeof(u32));
    const size_t off_ovf    = align16(off_counts + (size_t)EB * R * sizeof(u32));
    const size_t off_cop    = align16(off_ovf + (size_t)R * RS * sizeof(float));

    int C = 0, CAP = 0;
    if (R >= 1 && R <= MAX_R && n_nodes <= MAX_NODES) {
        C = 256 / R;                                     // one balanced round
        const size_t off_seg = align16(off_cop + (size_t)C * R * RS * sizeof(float));
        if (ws_size > off_seg) {
            size_t cap = (ws_size - off_seg) / ((size_t)EB * R * sizeof(u32));
            cap &= ~(size_t)255;
            if (cap > (size_t)W) cap = W;
            CAP = (int)cap;
        }
    }

    if (C > 0 && CAP >= 2048) {
        char* ws = (char*)d_ws;
        u32*   zw     = (u32*)(ws + off_zw);
        u32*   counts = (u32*)(ws + off_counts);
        float* ovf    = (float*)(ws + off_ovf);
        float* copies = (float*)(ws + off_cop);
        const size_t off_seg = align16(off_cop + (size_t)C * R * RS * sizeof(float));
        u32*   seg    = (u32*)(ws + off_seg);

        hipMemsetAsync(ovf, 0, (size_t)R * RS * sizeof(float), stream);
        k_pack<<<(n_words + 255) / 256, 256, 0, stream>>>(z, zw, n_words, n_nodes);
        k_split<<<EB, 1024, 0, stream>>>(
            zw, dist, sender, recv, a_factor, z_power, coefs, exps, cradii,
            seg, counts, ovf, n_edges, n_words, W, CAP, R);
        k_accum2<<<C * R, 1024, 0, stream>>>(seg, counts, copies, C, R, CAP);
        k_final2<<<(n_nodes + 255) / 256, 256, 0, stream>>>(
            copies, ovf, out, n_nodes, C, R * RS);
    } else if (n_nodes <= MAX_NODES &&
               ws_size >= (size_t)n_words * sizeof(u32)) {
        u32* zw = (u32*)d_ws;
        hipMemsetAsync(out, 0, (size_t)n_nodes * sizeof(float), stream);
        k_pack<<<(n_words + 255) / 256, 256, 0, stream>>>(z, zw, n_words, n_nodes);
        zbl_edge_lds<<<256, 1024, 0, stream>>>(
            zw, dist, sender, recv, a_factor, z_power, coefs, exps, cradii,
            out, n_edges, n_words);
    }
}